// Round 2
// baseline (3975.796 us; speedup 1.0000x reference)
//
#include <hip/hip_runtime.h>
#include <math.h>

// ---- problem constants (match reference) ----
#define NCOLS   407
#define RAD_OFF 87
#define ANG_OFF 151

// shiftR[r] = 0.8 + r*0.275  (r=0..15)
// shiftA[a] = 0.8 + a*0.675  (a=0..3)
// shiftZ[z] = pi/8 + z*pi/4  (z=0..3)

__global__ __launch_bounds__(256) void init_out_kernel(const int* __restrict__ species,
                                                       float* __restrict__ out, int total) {
    int idx = blockIdx.x * 256 + threadIdx.x;
    if (idx >= total) return;
    int n = idx / NCOLS;
    int c = idx - n * NCOLS;
    // one-hot occupies columns [0,87); species[n] in [0,87)
    out[idx] = (c == species[n]) ? 1.0f : 0.0f;
}

__global__ __launch_bounds__(256) void radial_kernel(const float* __restrict__ dist,
                                                     const float* __restrict__ sw,
                                                     const int* __restrict__ esrc,
                                                     const int* __restrict__ edst,
                                                     const int* __restrict__ species,
                                                     const float4* __restrict__ valence,
                                                     float* __restrict__ out, int n_edges) {
    int e = blockIdx.x * 256 + threadIdx.x;
    if (e >= n_edges) return;
    float d = dist[e];
    float s = sw[e];
    int asrc = esrc[e];
    int adst = edst[e];
    float4 val = valence[species[adst]];
    float* o = out + (size_t)asrc * NCOLS + RAD_OFF;
    #pragma unroll
    for (int r = 0; r < 16; ++r) {
        float shift = 0.8f + 0.275f * (float)r;
        float x = d - shift;
        float t = 0.25f * __expf(-16.0f * x * x) * s;
        // term < 1e-7 contributes < ~1e-5 total per output element; threshold is 0.106
        if (t > 1e-7f) {
            atomicAdd(o + r * 4 + 0, t * val.x);
            atomicAdd(o + r * 4 + 1, t * val.y);
            atomicAdd(o + r * 4 + 2, t * val.z);
            atomicAdd(o + r * 4 + 3, t * val.w);
        }
    }
}

__global__ __launch_bounds__(256) void angular_kernel(const float* __restrict__ ang_angles,
                                                      const float* __restrict__ ang_dist,
                                                      const float* __restrict__ ang_sw,
                                                      const int* __restrict__ ang_edge_dst,
                                                      const int* __restrict__ asrc,
                                                      const int* __restrict__ adst,
                                                      const int* __restrict__ central,
                                                      const int* __restrict__ species,
                                                      const float4* __restrict__ valence,
                                                      float* __restrict__ out, int n_pairs) {
    int p = blockIdx.x * 256 + threadIdx.x;
    if (p >= n_pairs) return;
    int e1 = asrc[p];
    int e2 = adst[p];
    float d12  = 0.5f * (ang_dist[e1] + ang_dist[e2]);
    float ang  = ang_angles[p];
    float swp  = 2.0f * ang_sw[e1] * ang_sw[e2];
    float4 v1 = valence[species[ang_edge_dst[e1]]];
    float4 v2 = valence[species[ang_edge_dst[e2]]];

    float vp[4] = {v1.x + v2.x, v1.y + v2.y, v1.z + v2.z, v1.w + v2.w};
    float vm[4] = {v1.x * v2.x, v1.y * v2.y, v1.z * v2.z, v1.w * v2.w};
    float va[16];
    #pragma unroll
    for (int i = 0; i < 4; ++i)
        #pragma unroll
        for (int j = 0; j < 4; ++j)
            va[i * 4 + j] = vp[i] * vm[j];

    float f1[4];
    #pragma unroll
    for (int z = 0; z < 4; ++z) {
        float shift = (float)(M_PI / 8.0 + (double)z * M_PI / 4.0);
        float y = 0.5f + 0.5f * cosf(ang - shift);
        float y2 = y * y, y4 = y2 * y2, y8 = y4 * y4, y16 = y8 * y8;
        f1[z] = y16 * y16;  // y^32
    }
    float f2[4];
    #pragma unroll
    for (int a = 0; a < 4; ++a) {
        float x = d12 - (0.8f + 0.675f * (float)a);
        f2[a] = __expf(-8.0f * x * x);
    }

    float* o = out + (size_t)central[p] * NCOLS + ANG_OFF;
    #pragma unroll
    for (int a = 0; a < 4; ++a) {
        #pragma unroll
        for (int z = 0; z < 4; ++z) {
            float term = f2[a] * f1[z] * swp;
            // dropped mass per output element < ~1e-4; threshold is 0.106
            if (term > 6e-7f) {
                float* ot = o + (a * 4 + z) * 16;
                #pragma unroll
                for (int k = 0; k < 16; ++k)
                    atomicAdd(ot + k, term * va[k]);
            }
        }
    }
}

extern "C" void kernel_launch(void* const* d_in, const int* in_sizes, int n_in,
                              void* d_out, int out_size, void* d_ws, size_t ws_size,
                              hipStream_t stream) {
    const int*   species      = (const int*)  d_in[0];
    const float* distances    = (const float*)d_in[1];
    const float* switch_      = (const float*)d_in[2];
    const int*   edge_src     = (const int*)  d_in[3];
    const int*   edge_dst     = (const int*)  d_in[4];
    const float* ang_angles   = (const float*)d_in[5];
    const float* ang_dist     = (const float*)d_in[6];
    const float* ang_switch   = (const float*)d_in[7];
    const int*   ang_edge_dst = (const int*)  d_in[8];
    const int*   angle_src    = (const int*)  d_in[9];
    const int*   angle_dst    = (const int*)  d_in[10];
    const int*   central_atom = (const int*)  d_in[11];
    const float4* valence     = (const float4*)d_in[12];

    float* out = (float*)d_out;

    const int n_edges = in_sizes[1];
    const int n_pairs = in_sizes[5];
    const int total   = out_size;  // N_ATOMS * 407

    init_out_kernel<<<(total + 255) / 256, 256, 0, stream>>>(species, out, total);
    radial_kernel<<<(n_edges + 255) / 256, 256, 0, stream>>>(
        distances, switch_, edge_src, edge_dst, species, valence, out, n_edges);
    angular_kernel<<<(n_pairs + 255) / 256, 256, 0, stream>>>(
        ang_angles, ang_dist, ang_switch, ang_edge_dst, angle_src, angle_dst,
        central_atom, species, valence, out, n_pairs);
}

// Round 3
// 270.269 us; speedup vs baseline: 14.7105x; 14.7105x over previous
//
#include <hip/hip_runtime.h>
#include <math.h>

// ---- problem constants (match reference) ----
#define NCOLS   407
#define RAD_OFF 87
#define ANG_OFF 151

// shiftR[r] = 0.8 + r*0.275  (r=0..15)
// shiftA[a] = 0.8 + a*0.675  (a=0..3)
// shiftZ[z] = pi/8 + z*pi/4  (z=0..3)

// ============ one-hot ============
__global__ __launch_bounds__(256) void onehot_kernel(const int* __restrict__ species,
                                                     float* __restrict__ out, int n_atoms) {
    int idx = blockIdx.x * 256 + threadIdx.x;
    int total = n_atoms * 87;
    if (idx >= total) return;
    int n = idx / 87;
    int c = idx - n * 87;
    out[(size_t)n * NCOLS + c] = (c == species[n]) ? 1.0f : 0.0f;
}

// ============ histogram ============
__global__ __launch_bounds__(256) void hist_kernel(const int* __restrict__ idx,
                                                   int* __restrict__ counts, int n) {
    int i = blockIdx.x * 256 + threadIdx.x;
    if (i < n) atomicAdd(&counts[idx[i]], 1);
}

// ============ single-block exclusive scan (n <= 1024*C) ============
__global__ __launch_bounds__(1024) void scan_kernel(const int* __restrict__ counts,
                                                    int* __restrict__ offsets,
                                                    int* __restrict__ cursor, int n) {
    __shared__ int part[1024];
    int t = threadIdx.x;
    int C = (n + 1023) >> 10;
    int lo = t * C;
    int hi = min(lo + C, n);
    int s = 0;
    for (int i = lo; i < hi; ++i) s += counts[i];
    part[t] = s;
    __syncthreads();
    for (int off = 1; off < 1024; off <<= 1) {
        int v = (t >= off) ? part[t - off] : 0;
        __syncthreads();
        part[t] += v;
        __syncthreads();
    }
    int run = part[t] - s;   // exclusive base
    for (int i = lo; i < hi; ++i) {
        offsets[i] = run;
        cursor[i]  = run;
        run += counts[i];
    }
    if (t == 1023) offsets[n] = part[1023];
}

// ============ radial phase A: per-edge payload into CSR slots ============
// payload per edge (8 floats): [d, 0.25*s, v0, v1, v2, v3, 0, 0]
__global__ __launch_bounds__(256) void rad_phaseA(const float* __restrict__ dist,
                                                  const float* __restrict__ sw,
                                                  const int* __restrict__ esrc,
                                                  const int* __restrict__ edst,
                                                  const int* __restrict__ species,
                                                  const float4* __restrict__ valence,
                                                  int* __restrict__ cursor,
                                                  float4* __restrict__ payload, int n_edges) {
    int e = blockIdx.x * 256 + threadIdx.x;
    if (e >= n_edges) return;
    float d  = dist[e];
    float ps = 0.25f * sw[e];
    int a = esrc[e];
    float4 v = valence[species[edst[e]]];
    int slot = atomicAdd(&cursor[a], 1);
    float4* p = payload + (size_t)slot * 2;
    p[0] = make_float4(d, ps, v.x, v.y);
    p[1] = make_float4(v.z, v.w, 0.0f, 0.0f);
}

// ============ angular phase A: per-pair payload into CSR slots ============
// payload per pair (16 floats): [f2s0..3 | f10..3 | vp0..3 | vm0..3]
__global__ __launch_bounds__(256) void ang_phaseA(const float* __restrict__ ang_angles,
                                                  const float* __restrict__ ang_dist,
                                                  const float* __restrict__ ang_sw,
                                                  const int* __restrict__ ang_edge_dst,
                                                  const int* __restrict__ psrc,
                                                  const int* __restrict__ pdst,
                                                  const int* __restrict__ central,
                                                  const int* __restrict__ species,
                                                  const float4* __restrict__ valence,
                                                  int* __restrict__ cursor,
                                                  float4* __restrict__ payload, int n_pairs) {
    int p = blockIdx.x * 256 + threadIdx.x;
    if (p >= n_pairs) return;
    int e1 = psrc[p];
    int e2 = pdst[p];
    float d12 = 0.5f * (ang_dist[e1] + ang_dist[e2]);
    float swp = 2.0f * ang_sw[e1] * ang_sw[e2];
    float4 v1 = valence[species[ang_edge_dst[e1]]];
    float4 v2 = valence[species[ang_edge_dst[e2]]];

    float sa, ca;
    __sincosf(ang_angles[p], &sa, &ca);
    // cos(ang - shiftZ) = ca*cos(shiftZ) + sa*sin(shiftZ)
    const float czv[4] = { 0.92387953f,  0.38268343f, -0.38268343f, -0.92387953f };
    const float szv[4] = { 0.38268343f,  0.92387953f,  0.92387953f,  0.38268343f };
    float f1[4];
    #pragma unroll
    for (int z = 0; z < 4; ++z) {
        float y = 0.5f + 0.5f * (ca * czv[z] + sa * szv[z]);
        float y2 = y * y, y4 = y2 * y2, y8 = y4 * y4, y16 = y8 * y8;
        f1[z] = y16 * y16;
    }
    float f2s[4];
    #pragma unroll
    for (int a = 0; a < 4; ++a) {
        float x = d12 - (0.8f + 0.675f * (float)a);
        f2s[a] = swp * __expf(-8.0f * x * x);
    }

    int c = central[p];
    int slot = atomicAdd(&cursor[c], 1);
    float4* q = payload + (size_t)slot * 4;
    q[0] = make_float4(f2s[0], f2s[1], f2s[2], f2s[3]);
    q[1] = make_float4(f1[0], f1[1], f1[2], f1[3]);
    q[2] = make_float4(v1.x + v2.x, v1.y + v2.y, v1.z + v2.z, v1.w + v2.w);
    q[3] = make_float4(v1.x * v2.x, v1.y * v2.y, v1.z * v2.z, v1.w * v2.w);
}

// ============ radial phase B: gather per atom (64 threads = 64 columns) ============
__global__ __launch_bounds__(64) void rad_phaseB(const float* __restrict__ payload,
                                                 const int* __restrict__ offsets,
                                                 float* __restrict__ out) {
    int atom = blockIdx.x;
    int t = threadIdx.x;
    int beg = offsets[atom];
    int end = offsets[atom + 1];
    __shared__ float buf[64];
    int r = t >> 2, k = t & 3;
    float shift = 0.8f + 0.275f * (float)r;
    float acc = 0.0f;
    for (int base = beg; base < end; base += 8) {
        int cnt = min(8, end - base);
        if (t < cnt * 8) buf[t] = payload[(size_t)base * 8 + t];
        __syncthreads();
        if (cnt == 8) {
            #pragma unroll
            for (int e = 0; e < 8; ++e) {
                float d = buf[e * 8 + 0];
                float ps = buf[e * 8 + 1];
                float v = buf[e * 8 + 2 + k];
                float x = d - shift;
                acc += ps * __expf(-16.0f * x * x) * v;
            }
        } else {
            for (int e = 0; e < cnt; ++e) {
                float d = buf[e * 8 + 0];
                float ps = buf[e * 8 + 1];
                float v = buf[e * 8 + 2 + k];
                float x = d - shift;
                acc += ps * __expf(-16.0f * x * x) * v;
            }
        }
        __syncthreads();
    }
    out[(size_t)atom * NCOLS + RAD_OFF + t] = acc;
}

// ============ angular phase B: gather per atom (256 threads = 256 columns) ============
__global__ __launch_bounds__(256) void ang_phaseB(const float* __restrict__ payload,
                                                  const int* __restrict__ offsets,
                                                  float* __restrict__ out) {
    int atom = blockIdx.x;
    int t = threadIdx.x;
    int beg = offsets[atom];
    int end = offsets[atom + 1];
    __shared__ float buf[256];
    // column = (a*4+z)*16 + (i*4+j)
    int a = t >> 6, z = (t >> 4) & 3, i = (t >> 2) & 3, j = t & 3;
    float acc = 0.0f;
    for (int base = beg; base < end; base += 16) {
        int cnt = min(16, end - base);
        if (t < cnt * 16) buf[t] = payload[(size_t)base * 16 + t];
        __syncthreads();
        if (cnt == 16) {
            #pragma unroll
            for (int e = 0; e < 16; ++e) {
                float f2s = buf[e * 16 + a];
                float f1  = buf[e * 16 + 4 + z];
                float vp  = buf[e * 16 + 8 + i];
                float vm  = buf[e * 16 + 12 + j];
                acc += (f2s * f1) * (vp * vm);
            }
        } else {
            for (int e = 0; e < cnt; ++e) {
                float f2s = buf[e * 16 + a];
                float f1  = buf[e * 16 + 4 + z];
                float vp  = buf[e * 16 + 8 + i];
                float vm  = buf[e * 16 + 12 + j];
                acc += (f2s * f1) * (vp * vm);
            }
        }
        __syncthreads();
    }
    out[(size_t)atom * NCOLS + ANG_OFF + t] = acc;
}

extern "C" void kernel_launch(void* const* d_in, const int* in_sizes, int n_in,
                              void* d_out, int out_size, void* d_ws, size_t ws_size,
                              hipStream_t stream) {
    const int*   species      = (const int*)  d_in[0];
    const float* distances    = (const float*)d_in[1];
    const float* switch_      = (const float*)d_in[2];
    const int*   edge_src     = (const int*)  d_in[3];
    const int*   edge_dst     = (const int*)  d_in[4];
    const float* ang_angles   = (const float*)d_in[5];
    const float* ang_dist     = (const float*)d_in[6];
    const float* ang_switch   = (const float*)d_in[7];
    const int*   ang_edge_dst = (const int*)  d_in[8];
    const int*   angle_src    = (const int*)  d_in[9];
    const int*   angle_dst    = (const int*)  d_in[10];
    const int*   central_atom = (const int*)  d_in[11];
    const float4* valence     = (const float4*)d_in[12];

    float* out = (float*)d_out;

    const int n_atoms = in_sizes[0];
    const int n_edges = in_sizes[1];
    const int n_pairs = in_sizes[5];

    // ---- workspace layout (16B-aligned sections) ----
    char* ws = (char*)d_ws;
    size_t off = 0;
    auto alloc = [&](size_t bytes) -> void* {
        void* p = ws + off;
        off = (off + bytes + 15) & ~(size_t)15;
        return p;
    };
    float4* ang_payload = (float4*)alloc((size_t)n_pairs * 16 * sizeof(float));
    float4* rad_payload = (float4*)alloc((size_t)n_edges * 8 * sizeof(float));
    int* rad_counts  = (int*)alloc((size_t)n_atoms * sizeof(int));
    int* ang_counts  = (int*)alloc((size_t)n_atoms * sizeof(int));
    int* rad_offsets = (int*)alloc((size_t)(n_atoms + 1) * sizeof(int));
    int* rad_cursor  = (int*)alloc((size_t)n_atoms * sizeof(int));
    int* ang_offsets = (int*)alloc((size_t)(n_atoms + 1) * sizeof(int));
    int* ang_cursor  = (int*)alloc((size_t)n_atoms * sizeof(int));
    // (required ws ≈ 57 MB; assumed available)

    hipMemsetAsync(rad_counts, 0, (size_t)n_atoms * sizeof(int), stream);
    hipMemsetAsync(ang_counts, 0, (size_t)n_atoms * sizeof(int), stream);

    hist_kernel<<<(n_edges + 255) / 256, 256, 0, stream>>>(edge_src, rad_counts, n_edges);
    hist_kernel<<<(n_pairs + 255) / 256, 256, 0, stream>>>(central_atom, ang_counts, n_pairs);

    scan_kernel<<<1, 1024, 0, stream>>>(rad_counts, rad_offsets, rad_cursor, n_atoms);
    scan_kernel<<<1, 1024, 0, stream>>>(ang_counts, ang_offsets, ang_cursor, n_atoms);

    rad_phaseA<<<(n_edges + 255) / 256, 256, 0, stream>>>(
        distances, switch_, edge_src, edge_dst, species, valence, rad_cursor, rad_payload, n_edges);
    ang_phaseA<<<(n_pairs + 255) / 256, 256, 0, stream>>>(
        ang_angles, ang_dist, ang_switch, ang_edge_dst, angle_src, angle_dst,
        central_atom, species, valence, ang_cursor, ang_payload, n_pairs);

    onehot_kernel<<<(n_atoms * 87 + 255) / 256, 256, 0, stream>>>(species, out, n_atoms);

    rad_phaseB<<<n_atoms, 64, 0, stream>>>((const float*)rad_payload, rad_offsets, out);
    ang_phaseB<<<n_atoms, 256, 0, stream>>>((const float*)ang_payload, ang_offsets, out);
}

// Round 4
// 231.396 us; speedup vs baseline: 17.1818x; 1.1680x over previous
//
#include <hip/hip_runtime.h>
#include <math.h>

// ---- problem constants (match reference) ----
#define NCOLS   407
#define RAD_OFF 87
#define ANG_OFF 151

// shiftR[r] = 0.8 + r*0.275  (r=0..15)
// shiftA[a] = 0.8 + a*0.675  (a=0..3)
// shiftZ[z] = pi/8 + z*pi/4  (z=0..3)

// ============ init: zero counts (2N ints) + one-hot ============
__global__ __launch_bounds__(256) void init_kernel(const int* __restrict__ species,
                                                   float* __restrict__ out,
                                                   int* __restrict__ counts,
                                                   int n_atoms) {
    int idx = blockIdx.x * 256 + threadIdx.x;
    if (idx < 2 * n_atoms) counts[idx] = 0;
    int total = n_atoms * 87;
    if (idx < total) {
        int n = idx / 87;
        int c = idx - n * 87;
        out[(size_t)n * NCOLS + c] = (c == species[n]) ? 1.0f : 0.0f;
    }
}

// ============ fused histogram ============
__global__ __launch_bounds__(256) void hist_kernel(const int* __restrict__ esrc,
                                                   const int* __restrict__ central,
                                                   int* __restrict__ rad_counts,
                                                   int* __restrict__ ang_counts,
                                                   int n_edges, int n_pairs) {
    int i = blockIdx.x * 256 + threadIdx.x;
    if (i < n_edges) {
        atomicAdd(&rad_counts[esrc[i]], 1);
    } else {
        int p = i - n_edges;
        if (p < n_pairs) atomicAdd(&ang_counts[central[p]], 1);
    }
}

// ============ fused scan: block 0 = radial, block 1 = angular ============
// counts[] is overwritten in-place with the exclusive prefix (serves as cursor)
__global__ __launch_bounds__(1024) void scan_kernel(int* __restrict__ rad_counts,
                                                    int* __restrict__ ang_counts,
                                                    int* __restrict__ rad_offsets,
                                                    int* __restrict__ ang_offsets,
                                                    int n) {
    int* counts  = (blockIdx.x == 0) ? rad_counts  : ang_counts;
    int* offsets = (blockIdx.x == 0) ? rad_offsets : ang_offsets;
    __shared__ int part[1024];
    int t = threadIdx.x;
    int C = (n + 1023) >> 10;
    int lo = min(t * C, n);
    int hi = min(lo + C, n);
    int s = 0;
    for (int i = lo; i < hi; ++i) s += counts[i];
    part[t] = s;
    __syncthreads();
    for (int off = 1; off < 1024; off <<= 1) {
        int v = (t >= off) ? part[t - off] : 0;
        __syncthreads();
        part[t] += v;
        __syncthreads();
    }
    int run = part[t] - s;   // exclusive base for this thread's range
    for (int i = lo; i < hi; ++i) {
        int c = counts[i];
        offsets[i] = run;
        counts[i]  = run;    // cursor
        run += c;
    }
    if (t == 1023) offsets[n] = part[1023];
}

// ============ fused phase A: coalesced payload in input order + perm scatter ============
// radial payload: ds[e]=(d, 0.25*s), v[e]=valence4   angular payload: 16 floats/pair
__global__ __launch_bounds__(256) void phaseA_kernel(
    const float* __restrict__ dist, const float* __restrict__ sw,
    const int* __restrict__ esrc, const int* __restrict__ edst,
    const float* __restrict__ ang_angles, const float* __restrict__ ang_dist,
    const float* __restrict__ ang_sw, const int* __restrict__ ang_edge_dst,
    const int* __restrict__ psrc, const int* __restrict__ pdst,
    const int* __restrict__ central,
    const int* __restrict__ species, const float4* __restrict__ valence,
    int* __restrict__ rad_cursor, int* __restrict__ ang_cursor,
    float2* __restrict__ rad_pay_ds, float4* __restrict__ rad_pay_v,
    int* __restrict__ rad_perm,
    float4* __restrict__ ang_payload, int* __restrict__ ang_perm,
    int n_edges, int n_pairs)
{
    int i = blockIdx.x * 256 + threadIdx.x;
    if (i < n_edges) {
        float d  = dist[i];
        float ps = 0.25f * sw[i];
        float4 v = valence[species[edst[i]]];
        rad_pay_ds[i] = make_float2(d, ps);
        rad_pay_v[i]  = v;
        int slot = atomicAdd(&rad_cursor[esrc[i]], 1);
        rad_perm[slot] = i;
    } else {
        int p = i - n_edges;
        if (p >= n_pairs) return;
        int e1 = psrc[p];
        int e2 = pdst[p];
        float d12 = 0.5f * (ang_dist[e1] + ang_dist[e2]);
        float swp = 2.0f * ang_sw[e1] * ang_sw[e2];
        float4 v1 = valence[species[ang_edge_dst[e1]]];
        float4 v2 = valence[species[ang_edge_dst[e2]]];

        float sa, ca;
        __sincosf(ang_angles[p], &sa, &ca);
        // cos(ang - shiftZ) = ca*cos(shiftZ) + sa*sin(shiftZ)
        const float czv[4] = { 0.92387953f,  0.38268343f, -0.38268343f, -0.92387953f };
        const float szv[4] = { 0.38268343f,  0.92387953f,  0.92387953f,  0.38268343f };
        float f1[4];
        #pragma unroll
        for (int z = 0; z < 4; ++z) {
            float y = 0.5f + 0.5f * (ca * czv[z] + sa * szv[z]);
            float y2 = y * y, y4 = y2 * y2, y8 = y4 * y4, y16 = y8 * y8;
            f1[z] = y16 * y16;  // y^32
        }
        float f2s[4];
        #pragma unroll
        for (int a = 0; a < 4; ++a) {
            float x = d12 - (0.8f + 0.675f * (float)a);
            f2s[a] = swp * __expf(-8.0f * x * x);
        }

        float4* q = ang_payload + (size_t)p * 4;
        q[0] = make_float4(f2s[0], f2s[1], f2s[2], f2s[3]);
        q[1] = make_float4(f1[0], f1[1], f1[2], f1[3]);
        q[2] = make_float4(v1.x + v2.x, v1.y + v2.y, v1.z + v2.z, v1.w + v2.w);
        q[3] = make_float4(v1.x * v2.x, v1.y * v2.y, v1.z * v2.z, v1.w * v2.w);

        int slot = atomicAdd(&ang_cursor[central[p]], 1);
        ang_perm[slot] = p;
    }
}

// ============ radial phase B: gather via perm (64 threads = 64 columns) ============
__global__ __launch_bounds__(64) void rad_phaseB(const float2* __restrict__ pay_ds,
                                                 const float4* __restrict__ pay_v,
                                                 const int* __restrict__ perm,
                                                 const int* __restrict__ offsets,
                                                 float* __restrict__ out) {
    int atom = blockIdx.x;
    int t = threadIdx.x;
    int beg = offsets[atom];
    int end = offsets[atom + 1];
    __shared__ float buf[64];
    int r = t >> 2, k = t & 3;
    float shift = 0.8f + 0.275f * (float)r;
    int g = t >> 3, j = t & 7;   // 8 edges/chunk, 8 lanes per edge (2 pad)
    float acc = 0.0f;
    for (int base = beg; base < end; base += 8) {
        int rem = end - base;
        if (g < rem) {
            int pp = perm[base + g];   // 8 lanes broadcast-read same address
            float x = 0.0f;
            if (j < 2)      x = ((const float*)pay_ds)[(size_t)pp * 2 + j];
            else if (j < 6) x = ((const float*)pay_v)[(size_t)pp * 4 + (j - 2)];
            buf[t] = x;
        }
        __syncthreads();
        int cnt = min(8, rem);
        if (cnt == 8) {
            #pragma unroll
            for (int e = 0; e < 8; ++e) {
                float d = buf[e * 8 + 0];
                float ps = buf[e * 8 + 1];
                float v = buf[e * 8 + 2 + k];
                float x = d - shift;
                acc += ps * __expf(-16.0f * x * x) * v;
            }
        } else {
            for (int e = 0; e < cnt; ++e) {
                float d = buf[e * 8 + 0];
                float ps = buf[e * 8 + 1];
                float v = buf[e * 8 + 2 + k];
                float x = d - shift;
                acc += ps * __expf(-16.0f * x * x) * v;
            }
        }
        __syncthreads();
    }
    out[(size_t)atom * NCOLS + RAD_OFF + t] = acc;
}

// ============ angular phase B: gather via perm (256 threads = 256 columns) ============
__global__ __launch_bounds__(256) void ang_phaseB(const float* __restrict__ payload,
                                                  const int* __restrict__ perm,
                                                  const int* __restrict__ offsets,
                                                  float* __restrict__ out) {
    int atom = blockIdx.x;
    int t = threadIdx.x;
    int beg = offsets[atom];
    int end = offsets[atom + 1];
    __shared__ float buf[256];
    // column = (a*4+z)*16 + (i*4+j)
    int a = t >> 6, z = (t >> 4) & 3, i = (t >> 2) & 3, j = t & 3;
    int g = t >> 4, jj = t & 15;   // 16 pairs/chunk, 16 lanes per pair
    float acc = 0.0f;
    for (int base = beg; base < end; base += 16) {
        int rem = end - base;
        if (g < rem) {
            int pp = perm[base + g];  // 16 lanes broadcast-read same address
            buf[t] = payload[(size_t)pp * 16 + jj];  // one 64B line per 16-lane group
        }
        __syncthreads();
        int cnt = min(16, rem);
        if (cnt == 16) {
            #pragma unroll
            for (int e = 0; e < 16; ++e) {
                float f2s = buf[e * 16 + a];
                float f1  = buf[e * 16 + 4 + z];
                float vp  = buf[e * 16 + 8 + i];
                float vm  = buf[e * 16 + 12 + j];
                acc += (f2s * f1) * (vp * vm);
            }
        } else {
            for (int e = 0; e < cnt; ++e) {
                float f2s = buf[e * 16 + a];
                float f1  = buf[e * 16 + 4 + z];
                float vp  = buf[e * 16 + 8 + i];
                float vm  = buf[e * 16 + 12 + j];
                acc += (f2s * f1) * (vp * vm);
            }
        }
        __syncthreads();
    }
    out[(size_t)atom * NCOLS + ANG_OFF + t] = acc;
}

extern "C" void kernel_launch(void* const* d_in, const int* in_sizes, int n_in,
                              void* d_out, int out_size, void* d_ws, size_t ws_size,
                              hipStream_t stream) {
    const int*   species      = (const int*)  d_in[0];
    const float* distances    = (const float*)d_in[1];
    const float* switch_      = (const float*)d_in[2];
    const int*   edge_src     = (const int*)  d_in[3];
    const int*   edge_dst     = (const int*)  d_in[4];
    const float* ang_angles   = (const float*)d_in[5];
    const float* ang_dist     = (const float*)d_in[6];
    const float* ang_switch   = (const float*)d_in[7];
    const int*   ang_edge_dst = (const int*)  d_in[8];
    const int*   angle_src    = (const int*)  d_in[9];
    const int*   angle_dst    = (const int*)  d_in[10];
    const int*   central_atom = (const int*)  d_in[11];
    const float4* valence     = (const float4*)d_in[12];

    float* out = (float*)d_out;

    const int n_atoms = in_sizes[0];
    const int n_edges = in_sizes[1];
    const int n_pairs = in_sizes[5];

    // ---- workspace layout (16B-aligned sections), total ≈ 56.8 MB ----
    char* ws = (char*)d_ws;
    size_t off = 0;
    auto alloc = [&](size_t bytes) -> void* {
        void* p = ws + off;
        off = (off + bytes + 15) & ~(size_t)15;
        return p;
    };
    float4* ang_payload = (float4*)alloc((size_t)n_pairs * 16 * sizeof(float)); // 35.84 MB
    float4* rad_pay_v   = (float4*)alloc((size_t)n_edges * sizeof(float4));     // 10.24 MB
    float2* rad_pay_ds  = (float2*)alloc((size_t)n_edges * sizeof(float2));     //  5.12 MB
    int*    ang_perm    = (int*)  alloc((size_t)n_pairs * sizeof(int));         //  2.24 MB
    int*    rad_perm    = (int*)  alloc((size_t)n_edges * sizeof(int));         //  2.56 MB
    int*    counts      = (int*)  alloc((size_t)2 * n_atoms * sizeof(int));     //  0.16 MB
    int*    rad_offsets = (int*)  alloc((size_t)(n_atoms + 1) * sizeof(int));
    int*    ang_offsets = (int*)  alloc((size_t)(n_atoms + 1) * sizeof(int));
    int* rad_counts = counts;            // doubles as cursor after scan
    int* ang_counts = counts + n_atoms;  // doubles as cursor after scan

    init_kernel<<<(n_atoms * 87 + 255) / 256, 256, 0, stream>>>(species, out, counts, n_atoms);

    int n_work = n_edges + n_pairs;
    hist_kernel<<<(n_work + 255) / 256, 256, 0, stream>>>(
        edge_src, central_atom, rad_counts, ang_counts, n_edges, n_pairs);

    scan_kernel<<<2, 1024, 0, stream>>>(rad_counts, ang_counts, rad_offsets, ang_offsets, n_atoms);

    phaseA_kernel<<<(n_work + 255) / 256, 256, 0, stream>>>(
        distances, switch_, edge_src, edge_dst,
        ang_angles, ang_dist, ang_switch, ang_edge_dst,
        angle_src, angle_dst, central_atom,
        species, valence,
        rad_counts, ang_counts,
        rad_pay_ds, rad_pay_v, rad_perm,
        ang_payload, ang_perm,
        n_edges, n_pairs);

    rad_phaseB<<<n_atoms, 64, 0, stream>>>(rad_pay_ds, rad_pay_v, rad_perm, rad_offsets, out);
    ang_phaseB<<<n_atoms, 256, 0, stream>>>((const float*)ang_payload, ang_perm, ang_offsets, out);
}